// Round 35
// baseline (158.116 us; speedup 1.0000x reference)
//
#include <hip/hip_runtime.h>
#include <math.h>

// Problem constants (from reference)
#define BB   8      // batch
#define MM   4      // MAXM
#define DD   128    // DIM
#define NHH  8      // heads
#define QDD  16     // head dim
#define NN   256    // H*W
#define KO   128    // NH*QD
#define DTILE 8     // D-rows per out_kernel block

typedef float v2f __attribute__((ext_vector_type(2)));
#define PKFMA(a, b, c) __builtin_elementwise_fma((a), (b), (c))

typedef __attribute__((ext_vector_type(8))) short bf16x8;   // 8 bf16 (4 VGPR)
typedef __attribute__((ext_vector_type(4))) float f32x4;    // MFMA acc

__device__ inline unsigned short f2bf(float f) {            // RNE float->bf16
    union { float f; unsigned u; } v; v.f = f;
    unsigned r = v.u + 0x7FFF + ((v.u >> 16) & 1);
    return (unsigned short)(r >> 16);
}
__device__ inline float bf2f(unsigned short h) {
    union { unsigned u; float f; } v; v.u = ((unsigned)h) << 16;
    return v.f;
}
// split x = hi + lo (both bf16)
__device__ inline void bfsplit(float x, unsigned short& hi, unsigned short& lo) {
    hi = f2bf(x);
    lo = f2bf(x - bf2f(hi));
}
// e_mfma: (br | -bi<<16) -> (bi | br<<16)
__device__ inline bf16x8 derive_im(bf16x8 v) {
    union { bf16x8 v; unsigned u[4]; } in, out;
    in.v = v;
#pragma unroll
    for (int w = 0; w < 4; ++w)
        out.u[w] = ((in.u[w] >> 16) ^ 0x8000u) | (in.u[w] << 16);
    return out.v;
}
// a_mfma: (kx | ky<<16) -> (ky | (-kx)<<16)
__device__ inline bf16x8 derive_im2(bf16x8 v) {
    union { bf16x8 v; unsigned u[4]; } in, out;
    in.v = v;
#pragma unroll
    for (int w = 0; w < 4; ++w)
        out.u[w] = (in.u[w] >> 16) | ((in.u[w] ^ 0x8000u) << 16);
    return out.v;
}

// ---------------------------------------------------------------------------
// Kernel 0 (trig-free): pe[m,i,j] = exp(i*m*theta) = ((dx+i*dy)/r)^m.
// Only peIJ is needed now (PA fused into softmax; peT dead).
// ---------------------------------------------------------------------------
__global__ void pe_kernel(float2* __restrict__ peIJ) {
    int bid = blockIdx.x;           // m*N + i
    int m = bid >> 8;
    int i = bid & 255;
    int j = threadIdx.x;
    float dy = (float)((j >> 4) - (i >> 4));
    float dx = (float)((j & 15) - (i & 15));
    float r2 = dx * dx + dy * dy;
    float c1 = 1.f, s1 = 0.f;
    if (r2 > 0.f) {
        float rinv = rsqrtf(r2);
        c1 = dx * rinv; s1 = dy * rinv;
    }
    float c = 1.f, s = 0.f;
    for (int k = 0; k < m; ++k) {   // m is block-uniform (0..3)
        float nc = c * c1 - s * s1;
        s = c * s1 + s * c1;
        c = nc;
    }
    peIJ[(m * NN + i) * NN + j] = make_float2(c, s);
}

// ---------------------------------------------------------------------------
// Kernel 1 (merged convA+convB): blocks 0..95 = convA (emb -> A' split-bf16),
// blocks 96..351 = convB (x -> Bre split-bf16; Bim derived in e_mfma).
// ---------------------------------------------------------------------------
__global__ void convAB_kernel(const float* __restrict__ er, const float* __restrict__ ei,
                              const float* __restrict__ xr, const float* __restrict__ xi,
                              unsigned int* __restrict__ AbfHi, unsigned int* __restrict__ AbfLo,
                              unsigned int* __restrict__ BreHi, unsigned int* __restrict__ BreLo) {
    if (blockIdx.x < 96) {
        int tmh = blockIdx.x;             // 0..95
        int base = tmh * QDD * DD;
#pragma unroll
        for (int it = 0; it < 8; ++it) {
            int idx = threadIdx.x + it * 256;  // q*128+D
            float ar = er[base + idx];
            float ai = ei[base + idx];
            unsigned short arh, arl, aih, ail;
            bfsplit(ar, arh, arl);
            bfsplit(ai, aih, ail);
            AbfHi[base + idx] = (unsigned int)arh | ((unsigned int)aih << 16);
            AbfLo[base + idx] = (unsigned int)arl | ((unsigned int)ail << 16);
        }
        return;
    }
    int bid = blockIdx.x - 96;            // 0..255 = 32 bm x 8 Dg
    int bm = bid >> 3;
    int Dg = bid & 7;
    int D0 = Dg * 16;
    int tid = threadIdx.x;

    __shared__ float sxr[16][257];
    __shared__ float sxi[16][257];

    const float* xrp = xr + (size_t)bm * DD * NN;
    const float* xip = xi + (size_t)bm * DD * NN;
#pragma unroll
    for (int it = 0; it < 16; ++it) {
        int i2 = tid + it * 256;
        int r = i2 >> 8, c = i2 & 255;
        sxr[r][c] = xrp[(size_t)(D0 + r) * NN + c];
        sxi[r][c] = xip[(size_t)(D0 + r) * NN + c];
    }
    __syncthreads();

    int n = tid;
    unsigned int reh[16], rel_[16];
#pragma unroll
    for (int d = 0; d < 16; ++d) {
        float br = sxr[d][n];
        float bi = sxi[d][n];
        unsigned short brh, brl, bih, bil;
        bfsplit(br, brh, brl);
        bfsplit(bi, bih, bil);
        reh[d]  = (unsigned int)brh | ((unsigned int)(bih ^ 0x8000) << 16);
        rel_[d] = (unsigned int)brl | ((unsigned int)(bil ^ 0x8000) << 16);
    }
    size_t ob = (size_t)bm * 32768 + (size_t)n * 128 + D0;
#pragma unroll
    for (int w = 0; w < 4; ++w) {
        ((uint4*)(BreHi + ob))[w] = make_uint4(reh[4*w], reh[4*w+1], reh[4*w+2], reh[4*w+3]);
        ((uint4*)(BreLo + ob))[w] = make_uint4(rel_[4*w], rel_[4*w+1], rel_[4*w+2], rel_[4*w+3]);
    }
}

// ---------------------------------------------------------------------------
// Kernel 2 (e_mfma v5 = v4 + FUSED qe): block = (pair, h, nhalf).
// t=0 plane stays in registers: emits Ea fragments + QE (shfl-reduced);
// E float2 written for t=2 (V) ONLY. t=1 -> Kb fragments.
// ---------------------------------------------------------------------------
__global__ __launch_bounds__(256, 2)
void e_mfma_kernel(const unsigned short* __restrict__ AbfHi,
                   const unsigned short* __restrict__ AbfLo,
                   const unsigned short* __restrict__ BreHi,
                   const unsigned short* __restrict__ BreLo,
                   const float* __restrict__ encr, const float* __restrict__ enci,
                   float2* __restrict__ E,
                   float2* __restrict__ QE,
                   unsigned int* __restrict__ EaHi, unsigned int* __restrict__ EaLo,
                   unsigned int* __restrict__ KbHi, unsigned int* __restrict__ KbLo) {
    int bid = blockIdx.x;                 // 512 = 8 xcd x 64 idx
    int xcd = bid & 7;
    int idx = bid >> 3;                   // 0..63
    int pair = xcd * 4 + (idx & 3);       // b*MM+m (XCD-pinned B panels)
    int h = (idx >> 2) & 7;               // 0..7
    int nhalf = idx >> 5;                 // 0..1
    int b = pair >> 2, m = pair & 3;
    int tid = threadIdx.x;
    int wav = tid >> 6, lane = tid & 63;
    int lo = lane & 15, hi = lane >> 4;

    const unsigned short* AH[3];
    const unsigned short* AL[3];
#pragma unroll
    for (int t = 0; t < 3; ++t) {
        size_t aoff = ((size_t)((t * MM + m) * NHH + h)) * QDD * 256;
        AH[t] = AbfHi + aoff;
        AL[t] = AbfLo + aoff;
    }
    size_t boff = (size_t)pair * 256 * 256;
    const unsigned short* BrH = BreHi + boff;
    const unsigned short* BrL = BreLo + boff;

    f32x4 accRe[3][2], accIm[3][2];
#pragma unroll
    for (int t = 0; t < 3; ++t)
#pragma unroll
        for (int nt = 0; nt < 2; ++nt) {
            accRe[t][nt] = (f32x4)(0.f);
            accIm[t][nt] = (f32x4)(0.f);
        }

#pragma unroll
    for (int ks = 0; ks < 8; ++ks) {
        int k0 = ks * 32;
        int arow = lo * 256 + k0 + hi * 8;
        bf16x8 aH[3], aL[3];
#pragma unroll
        for (int t = 0; t < 3; ++t) {
            aH[t] = *(const bf16x8*)(AH[t] + arow);
            aL[t] = *(const bf16x8*)(AL[t] + arow);
        }
#pragma unroll
        for (int nt = 0; nt < 2; ++nt) {
            int n0 = nhalf * 128 + (wav * 2 + nt) * 16;
            size_t brow = (size_t)(n0 + lo) * 256 + k0 + hi * 8;
            bf16x8 brh = *(const bf16x8*)(BrH + brow);
            bf16x8 brl = *(const bf16x8*)(BrL + brow);
            bf16x8 bih = derive_im(brh);
            bf16x8 bil = derive_im(brl);
#pragma unroll
            for (int t = 0; t < 3; ++t) {
                accRe[t][nt] = __builtin_amdgcn_mfma_f32_16x16x32_bf16(aH[t], brh, accRe[t][nt], 0, 0, 0);
                accRe[t][nt] = __builtin_amdgcn_mfma_f32_16x16x32_bf16(aH[t], brl, accRe[t][nt], 0, 0, 0);
                accRe[t][nt] = __builtin_amdgcn_mfma_f32_16x16x32_bf16(aL[t], brh, accRe[t][nt], 0, 0, 0);
                accIm[t][nt] = __builtin_amdgcn_mfma_f32_16x16x32_bf16(aH[t], bih, accIm[t][nt], 0, 0, 0);
                accIm[t][nt] = __builtin_amdgcn_mfma_f32_16x16x32_bf16(aH[t], bil, accIm[t][nt], 0, 0, 0);
                accIm[t][nt] = __builtin_amdgcn_mfma_f32_16x16x32_bf16(aL[t], bih, accIm[t][nt], 0, 0, 0);
            }
        }
    }

    int bh = b * NHH + h;

    // --- fused qe: QE[b,m,h,i] = sum_q conj(E0[q,i])*enc0[m,h,q] ---
    {
        float cr[4], ci[4];
#pragma unroll
        for (int reg = 0; reg < 4; ++reg) {
            int q = hi * 4 + reg;
            int eb = (m * NHH + h) * QDD + q;
            cr[reg] = encr[eb];
            ci[reg] = enci[eb];
        }
#pragma unroll
        for (int nt = 0; nt < 2; ++nt) {
            int n0 = nhalf * 128 + (wav * 2 + nt) * 16;
            float sr = 0.f, si = 0.f;
#pragma unroll
            for (int reg = 0; reg < 4; ++reg) {
                float erv = accRe[0][nt][reg];
                float eiv = accIm[0][nt][reg];
                // conj(e)*c = (er*cr + ei*ci) + i(er*ci - ei*cr)
                sr = fmaf(erv, cr[reg], fmaf( eiv, ci[reg], sr));
                si = fmaf(erv, ci[reg], fmaf(-eiv, cr[reg], si));
            }
            sr += __shfl_xor(sr, 16); si += __shfl_xor(si, 16);
            sr += __shfl_xor(sr, 32); si += __shfl_xor(si, 32);
            if (hi == 0)
                QE[(size_t)((b * MM + m) * NHH + h) * NN + n0 + lo] = make_float2(sr, si);
        }
    }

    // t=0: Ea fragments ; t=1: Kb fragments ; t=2: E float2 (V).
#pragma unroll
    for (int t = 0; t < 3; ++t) {
        size_t ebase = (size_t)((((t * BB + b) * MM + m) * NHH + h) * QDD) * NN;
#pragma unroll
        for (int nt = 0; nt < 2; ++nt) {
            int n0 = nhalf * 128 + (wav * 2 + nt) * 16;
            if (t == 2) {
#pragma unroll
                for (int reg = 0; reg < 4; ++reg) {
                    int q = hi * 4 + reg;
                    E[ebase + (size_t)q * NN + n0 + lo] =
                        make_float2(accRe[t][nt][reg], accIm[t][nt][reg]);
                }
            }
            if (t < 2) {
                unsigned int hiU[4], loU[4];
#pragma unroll
                for (int reg = 0; reg < 4; ++reg) {
                    unsigned short rh, rl, ih, il;
                    bfsplit(accRe[t][nt][reg], rh, rl);
                    bfsplit(accIm[t][nt][reg], ih, il);
                    hiU[reg] = (unsigned int)rh | ((unsigned int)ih << 16);
                    loU[reg] = (unsigned int)rl | ((unsigned int)il << 16);
                }
                // r = n0/16, ks = m; uint off = (((r*4+ks)*64)+lane)*4
                int r = n0 >> 4;
                size_t fo = (size_t)bh * 16384 + (size_t)((r * 4 + m) * 64 + lane) * 4;
                unsigned int* tH = (t == 0) ? EaHi : KbHi;
                unsigned int* tL = (t == 0) ? EaLo : KbLo;
                *(uint4*)(tH + fo) = make_uint4(hiU[0], hiU[1], hiU[2], hiU[3]);
                *(uint4*)(tL + fo) = make_uint4(loU[0], loU[1], loU[2], loU[3]);
            }
        }
    }
}

// ---------------------------------------------------------------------------
// Kernel 3 (a_mfma v4, coalesced + j-split): 512 blocks.
// ---------------------------------------------------------------------------
__global__ __launch_bounds__(256, 2)
void a_mfma_kernel(const unsigned short* __restrict__ EaHi,
                   const unsigned short* __restrict__ EaLo,
                   const unsigned short* __restrict__ KbHi,
                   const unsigned short* __restrict__ KbLo,
                   const float2* __restrict__ QE,
                   const float2* __restrict__ peIJ,
                   float2* __restrict__ Scores) {
    int bid = blockIdx.x;                 // 512 = 8 xcd x 64 idx
    int xcd = bid & 7;
    int idx = bid >> 3;                   // 0..63
    int bh = xcd * 8 + (idx & 7);         // K-panel XCD-pinned
    int iquad = (idx >> 3) & 3;           // 0..3
    int jhalf = idx >> 5;                 // 0..1
    int b = bh >> 3, h = bh & 7;
    int tid = threadIdx.x;
    int wav = tid >> 6, lane = tid & 63;
    int lo = lane & 15, hi = lane >> 4;
    int it = iquad * 4 + wav;             // this wave's i-tile (0..15)

    const unsigned short* EaH = EaHi + (size_t)bh * 32768;
    const unsigned short* EaL = EaLo + (size_t)bh * 32768;
    const unsigned short* KbH = KbHi + (size_t)bh * 32768;
    const unsigned short* KbL = KbLo + (size_t)bh * 32768;

    f32x4 accRe[8], accIm[8];
#pragma unroll
    for (int nt = 0; nt < 8; ++nt) { accRe[nt] = (f32x4)(0.f); accIm[nt] = (f32x4)(0.f); }

#pragma unroll
    for (int ks = 0; ks < 4; ++ks) {
        size_t arow = (size_t)((it * 4 + ks) * 64 + lane) * 8;   // coalesced
        bf16x8 aH = *(const bf16x8*)(EaH + arow);
        bf16x8 aL = *(const bf16x8*)(EaL + arow);
#pragma unroll
        for (int nt = 0; nt < 8; ++nt) {
            int jt = jhalf * 8 + nt;
            size_t brow = (size_t)((jt * 4 + ks) * 64 + lane) * 8;  // coalesced
            bf16x8 brh = *(const bf16x8*)(KbH + brow);
            bf16x8 brl = *(const bf16x8*)(KbL + brow);
            bf16x8 bih = derive_im2(brh);
            bf16x8 bil = derive_im2(brl);
            accRe[nt] = __builtin_amdgcn_mfma_f32_16x16x32_bf16(aH, brh, accRe[nt], 0, 0, 0);
            accRe[nt] = __builtin_amdgcn_mfma_f32_16x16x32_bf16(aH, brl, accRe[nt], 0, 0, 0);
            accRe[nt] = __builtin_amdgcn_mfma_f32_16x16x32_bf16(aL, brh, accRe[nt], 0, 0, 0);
            accIm[nt] = __builtin_amdgcn_mfma_f32_16x16x32_bf16(aH, bih, accIm[nt], 0, 0, 0);
            accIm[nt] = __builtin_amdgcn_mfma_f32_16x16x32_bf16(aH, bil, accIm[nt], 0, 0, 0);
            accIm[nt] = __builtin_amdgcn_mfma_f32_16x16x32_bf16(aL, bih, accIm[nt], 0, 0, 0);
        }
    }

    // epilogue: + sum_m QE[b,m,h,i]*pe[m,i,j]; write Scores.
    float2 qe[MM][4];
#pragma unroll
    for (int m = 0; m < MM; ++m)
#pragma unroll
        for (int reg = 0; reg < 4; ++reg) {
            int i = it * 16 + hi * 4 + reg;
            qe[m][reg] = QE[(size_t)((b * MM + m) * NHH + h) * NN + i];
        }

#pragma unroll
    for (int nt = 0; nt < 8; ++nt) {
#pragma unroll
        for (int reg = 0; reg < 4; ++reg) {
            int i = it * 16 + hi * 4 + reg;
            int j = (jhalf * 8 + nt) * 16 + lo;
            float ar = accRe[nt][reg];
            float ai = accIm[nt][reg];
#pragma unroll
            for (int m = 0; m < MM; ++m) {
                float2 p = peIJ[(size_t)(m * NN + i) * NN + j];
                float2 e1 = qe[m][reg];
                ar = fmaf(e1.x, p.x, fmaf(-e1.y, p.y, ar));
                ai = fmaf(e1.x, p.y, fmaf( e1.y, p.x, ai));
            }
            Scores[(size_t)(bh * NN + i) * NN + j] = make_float2(ar, ai);
        }
    }
}

// ---------------------------------------------------------------------------
// Kernel 4 (v2, + fused PA): row softmax of |A|/4 over j -> AwT (transposed);
// also PA[b,m,h,i] = sum_j pe[m,i,j]*aw (4 complex row-reductions).
// ---------------------------------------------------------------------------
__global__ void softmax_kernel(const float2* __restrict__ A,
                               const float2* __restrict__ peIJ,
                               float* __restrict__ AwT,
                               float2* __restrict__ PA) {
    int row = blockIdx.x;                 // (b*NHH+h)*NN + i
    int j = threadIdx.x;
    float2 a = A[(size_t)row * NN + j];
    float v = sqrtf(fmaf(a.x, a.x, a.y * a.y)) * 0.25f;

    __shared__ float smax[4];
    __shared__ float ssum[4];
    __shared__ float sPA[4][2][4];        // [m][comp][wave]
    int lane = threadIdx.x & 63;
    int wid  = threadIdx.x >> 6;

    float mv = v;
#pragma unroll
    for (int off = 32; off > 0; off >>= 1) mv = fmaxf(mv, __shfl_xor(mv, off));
    if (lane == 0) smax[wid] = mv;
    __syncthreads();
    float mx = fmaxf(fmaxf(smax[0], smax[1]), fmaxf(smax[2], smax[3]));

    float e = expf(v - mx);
    float sv = e;
#pragma unroll
    for (int off = 32; off > 0; off >>= 1) sv += __shfl_xor(sv, off);
    if (lane == 0) ssum[wid] = sv;
    __syncthreads();
    float sum = ssum[0] + ssum[1] + ssum[2] + ssum[3];

    float aw = e / sum;
    int bh = row >> 8;
    int i  = row & 255;
    AwT[(size_t)(bh * NN + j) * NN + i] = aw;

    // fused PA: per m, reduce pe[m,i,j]*aw over the row
#pragma unroll
    for (int m = 0; m < MM; ++m) {
        float2 p = peIJ[(size_t)(m * NN + i) * NN + j];   // coalesced
        float pr = p.x * aw, pim = p.y * aw;
#pragma unroll
        for (int off = 32; off > 0; off >>= 1) {
            pr  += __shfl_xor(pr,  off);
            pim += __shfl_xor(pim, off);
        }
        if (lane == 0) { sPA[m][0][wid] = pr; sPA[m][1][wid] = pim; }
    }
    __syncthreads();
    if (j < MM) {                          // j = m
        int b = bh >> 3, h = bh & 7;
        float pr  = sPA[j][0][0] + sPA[j][0][1] + sPA[j][0][2] + sPA[j][0][3];
        float pim = sPA[j][1][0] + sPA[j][1][1] + sPA[j][1][2] + sPA[j][1][3];
        PA[(size_t)((b * MM + j) * NHH + h) * NN + i] = make_float2(pr, pim);
    }
}

// ---------------------------------------------------------------------------
// Kernel 5 (v4: qh-split + XCD swizzle, PA precomputed — no peT stream):
// res[b,m,h,q,i] = sum_j V[q,j]*Aw[i,j] + enc1[q]*PA[b,m,h,i].
// ---------------------------------------------------------------------------
__global__ __launch_bounds__(512)
void res_kernel(const float2* __restrict__ E, const float* __restrict__ AwT,
                const float2* __restrict__ PA,
                const float* __restrict__ encr, const float* __restrict__ enci,
                float2* __restrict__ Res) {
    int bid = blockIdx.x;
    int xcd = bid & 7;
    int idx = bid >> 3;                   // 0..63
    int bh = xcd * 8 + (idx & 7);         // b*NHH+h
    int mqh = idx >> 3;                   // 0..7
    int m  = mqh >> 1;
    int qh = mqh & 1;
    int h = bh & 7;
    int b = bh >> 3;
    int i = threadIdx.x & 255;
    int g = threadIdx.x >> 8;             // j-half 0/1

    __shared__ float2 sv[8][NN];          // 16 KB: this qh's 8 V rows
    __shared__ float2 spA[NN][8];         // 16 KB: g=1 partials (8 acc)
    __shared__ float2 senc[8];

    const float2* V = E + ((size_t)(((2 * BB + b) * MM + m) * NHH + h) * QDD + qh * 8) * NN;
    for (int i2 = threadIdx.x; i2 < 8 * NN; i2 += 512) sv[i2 >> 8][i2 & 255] = V[i2];
    if (threadIdx.x < 8) {
        int eb = ((MM + m) * NHH + h) * QDD + qh * 8 + threadIdx.x;   // enc[1,...]
        senc[threadIdx.x] = make_float2(encr[eb], enci[eb]);
    }
    __syncthreads();

    float accr[8], acci[8];
#pragma unroll
    for (int q = 0; q < 8; ++q) { accr[q] = 0.f; acci[q] = 0.f; }

    const float* awp = AwT + (size_t)((b * NHH + h) * NN) * NN + i;
    int j0 = g * (NN / 2);
    for (int j = j0; j < j0 + NN / 2; ++j) {
        float aw = awp[(size_t)j * NN];       // coalesced over i
#pragma unroll
        for (int q = 0; q < 8; ++q) {
            float2 vv = sv[q][j];             // wave-uniform -> broadcast
            accr[q] = fmaf(vv.x, aw, accr[q]);
            acci[q] = fmaf(vv.y, aw, acci[q]);
        }
    }

    if (g == 1) {
#pragma unroll
        for (int q = 0; q < 8; ++q) spA[i][q] = make_float2(accr[q], acci[q]);
    }
    __syncthreads();
    if (g == 0) {
#pragma unroll
        for (int q = 0; q < 8; ++q) {
            float2 o = spA[i][q];
            accr[q] += o.x; acci[q] += o.y;
        }
        float2 pa = PA[(size_t)((b * MM + m) * NHH + h) * NN + i];
        float par = pa.x, pai = pa.y;

        float2* rp = Res + ((size_t)((b * MM + m) * KO + h * QDD + qh * 8)) * NN + i;
#pragma unroll
        for (int q = 0; q < 8; ++q) {
            float2 e1 = senc[q];
            float rr = accr[q] + e1.x * par - e1.y * pai;
            float ri = acci[q] + e1.x * pai + e1.y * par;
            rp[(size_t)q * NN] = make_float2(rr, ri);
        }
    }
}

// ---------------------------------------------------------------------------
// Kernel 6 (DTILE=8 + XCD swizzle): out[b,m,D,n] = sum_k w_out*res.
// ---------------------------------------------------------------------------
__global__ void out_kernel(const float2* __restrict__ Res,
                           const float* __restrict__ wor, const float* __restrict__ woi,
                           float* __restrict__ out) {
    int bid = blockIdx.x;
    int xcd = bid & 7;
    int idx = bid >> 3;                   // 0..63
    int bm = xcd * 4 + (idx & 3);         // b*MM+m, 0..31
    int dt = idx >> 2;                    // 0..15
    int n = threadIdx.x;
    int D0 = dt * DTILE;
    int m = bm & 3;

    __shared__ float2 sw[DTILE][KO];      // 8 KB
    for (int i2 = threadIdx.x; i2 < DTILE * KO; i2 += 256) {
        int d = i2 >> 7, k = i2 & 127;
        int wb = (m * DD + D0 + d) * KO + k;
        sw[d][k] = make_float2(wor[wb], woi[wb]);
    }
    __syncthreads();

    const float2* rp = Res + (size_t)(bm * KO) * NN + n;
    float ar[DTILE], ai[DTILE];
#pragma unroll
    for (int d = 0; d < DTILE; ++d) { ar[d] = 0.f; ai[d] = 0.f; }

    for (int k = 0; k < KO; ++k) {
        float2 r = rp[(size_t)k * NN];    // coalesced
#pragma unroll
        for (int d = 0; d < DTILE; ++d) {
            float2 w = sw[d][k];          // broadcast
            ar[d] = fmaf(w.x, r.x, fmaf(-w.y, r.y, ar[d]));
            ai[d] = fmaf(w.x, r.y, fmaf( w.y, r.x, ai[d]));
        }
    }
#pragma unroll
    for (int d = 0; d < DTILE; ++d) {
        size_t ob = (size_t)(bm * DD + D0 + d) * NN + n;
        out[ob] = ar[d];
        out[(size_t)BB * MM * DD * NN + ob] = ai[d];
    }
}

// ---------------------------------------------------------------------------
extern "C" void kernel_launch(void* const* d_in, const int* in_sizes, int n_in,
                              void* d_out, int out_size, void* d_ws, size_t ws_size,
                              hipStream_t stream) {
    (void)in_sizes; (void)n_in; (void)out_size; (void)ws_size;

    const float* x_re   = (const float*)d_in[0];
    const float* x_im   = (const float*)d_in[1];
    const float* emb_re = (const float*)d_in[2];
    const float* emb_im = (const float*)d_in[3];
    const float* enc_re = (const float*)d_in[4];
    const float* enc_im = (const float*)d_in[5];
    const float* out_re = (const float*)d_in[6];
    const float* out_im = (const float*)d_in[7];
    float* out = (float*)d_out;

    // Workspace layout (floats). Total ~155.7 MB.
    float* ws = (float*)d_ws;
    size_t off = 0;
    float2* peIJ = (float2*)(ws + off); off += (size_t)MM * NN * NN * 2;          // 524288
    float2* peT  = (float2*)(ws + off); off += (size_t)MM * NN * NN * 2;          // 524288 (dead; hosts PA)
    float2* E    = (float2*)(ws + off); off += (size_t)3 * BB * MM * NHH * QDD * NN * 2; // 25165824
    float2* QE   = (float2*)(ws + off); off += (size_t)BB * MM * NHH * NN * 2;    // 131072
    float2* A    = (float2*)(ws + off); off += (size_t)BB * NHH * NN * NN * 2;    // 8388608 fl
    float*  AwT  = (float*)(ws + off);  off += (size_t)BB * NHH * NN * NN;        // 4194304 fl

    // Region plan (r34-verified + PA in dead peT region):
    //  1) convAB stages Abf/Bre in A region; e_mfma reads them ->
    //     writes E t2 (V) float2 + QE + Ea/Kb fragments into AwT region.
    //  2) a_mfma reads Ea/Kb(AwT region) -> Scores over FULL A region.
    //  3) softmax reads Scores(A)+peIJ -> writes AwT + PA (Ea/Kb dead).
    //  4) res reads AwT + PA + V(E t2) -> Res into A region start.
    unsigned int* AbfHi = (unsigned int*)A;
    unsigned int* AbfLo = AbfHi + (size_t)96 * QDD * DD;
    unsigned int* BreHi = AbfLo + (size_t)96 * QDD * DD;
    unsigned int* BreLo = BreHi + (size_t)32 * 256 * 128;

    unsigned int* EaHi = (unsigned int*)AwT;                      // 4 x 1048576 uints
    unsigned int* EaLo = EaHi + (size_t)64 * 16384;               //  = 16.78MB exact
    unsigned int* KbHi = EaLo + (size_t)64 * 16384;
    unsigned int* KbLo = KbHi + (size_t)64 * 16384;

    float2* Scores = A;   // full 33.5MB A region
    float2* Res    = A;   // first 8.4MB of A region, after Scores is dead
    float2* PA     = peT; // 1MB needed; peT region (2MB) is dead

    pe_kernel<<<MM * NN, 256, 0, stream>>>(peIJ);
    convAB_kernel<<<96 + 256, 256, 0, stream>>>(emb_re, emb_im, x_re, x_im,
                                                AbfHi, AbfLo, BreHi, BreLo);
    e_mfma_kernel<<<512, 256, 0, stream>>>(
        (const unsigned short*)AbfHi, (const unsigned short*)AbfLo,
        (const unsigned short*)BreHi, (const unsigned short*)BreLo,
        enc_re, enc_im, E, QE,
        EaHi, EaLo, KbHi, KbLo);
    a_mfma_kernel<<<512, 256, 0, stream>>>(
        (const unsigned short*)EaHi, (const unsigned short*)EaLo,
        (const unsigned short*)KbHi, (const unsigned short*)KbLo,
        QE, peIJ, Scores);
    softmax_kernel<<<BB * NHH * NN, 256, 0, stream>>>(Scores, peIJ, AwT, PA);
    res_kernel<<<BB * MM * NHH * 2, 512, 0, stream>>>(E, AwT, PA, enc_re, enc_im, Res);
    out_kernel<<<BB * MM * (DD / DTILE), 256, 0, stream>>>(Res, out_re, out_im, out);
}

// Round 36
// 135.949 us; speedup vs baseline: 1.1631x; 1.1631x over previous
//
#include <hip/hip_runtime.h>
#include <math.h>

// Problem constants (from reference)
#define BB   8      // batch
#define MM   4      // MAXM
#define DD   128    // DIM
#define NHH  8      // heads
#define QDD  16     // head dim
#define NN   256    // H*W
#define KO   128    // NH*QD
#define DTILE 8     // D-rows per out_kernel block

typedef float v2f __attribute__((ext_vector_type(2)));
#define PKFMA(a, b, c) __builtin_elementwise_fma((a), (b), (c))

typedef __attribute__((ext_vector_type(8))) short bf16x8;   // 8 bf16 (4 VGPR)
typedef __attribute__((ext_vector_type(4))) float f32x4;    // MFMA acc

__device__ inline unsigned short f2bf(float f) {            // RNE float->bf16
    union { float f; unsigned u; } v; v.f = f;
    unsigned r = v.u + 0x7FFF + ((v.u >> 16) & 1);
    return (unsigned short)(r >> 16);
}
__device__ inline float bf2f(unsigned short h) {
    union { unsigned u; float f; } v; v.u = ((unsigned)h) << 16;
    return v.f;
}
// split x = hi + lo (both bf16)
__device__ inline void bfsplit(float x, unsigned short& hi, unsigned short& lo) {
    hi = f2bf(x);
    lo = f2bf(x - bf2f(hi));
}
// e_mfma: (br | -bi<<16) -> (bi | br<<16)
__device__ inline bf16x8 derive_im(bf16x8 v) {
    union { bf16x8 v; unsigned u[4]; } in, out;
    in.v = v;
#pragma unroll
    for (int w = 0; w < 4; ++w)
        out.u[w] = ((in.u[w] >> 16) ^ 0x8000u) | (in.u[w] << 16);
    return out.v;
}
// a_mfma: (kx | ky<<16) -> (ky | (-kx)<<16)
__device__ inline bf16x8 derive_im2(bf16x8 v) {
    union { bf16x8 v; unsigned u[4]; } in, out;
    in.v = v;
#pragma unroll
    for (int w = 0; w < 4; ++w)
        out.u[w] = (in.u[w] >> 16) | ((in.u[w] ^ 0x8000u) << 16);
    return out.v;
}

// ---------------------------------------------------------------------------
// Kernel 0 (trig-free): pe[m,i,j] = exp(i*m*theta) = ((dx+i*dy)/r)^m.
// ---------------------------------------------------------------------------
__global__ void pe_kernel(float2* __restrict__ peIJ) {
    int bid = blockIdx.x;           // m*N + i
    int m = bid >> 8;
    int i = bid & 255;
    int j = threadIdx.x;
    float dy = (float)((j >> 4) - (i >> 4));
    float dx = (float)((j & 15) - (i & 15));
    float r2 = dx * dx + dy * dy;
    float c1 = 1.f, s1 = 0.f;
    if (r2 > 0.f) {
        float rinv = rsqrtf(r2);
        c1 = dx * rinv; s1 = dy * rinv;
    }
    float c = 1.f, s = 0.f;
    for (int k = 0; k < m; ++k) {   // m is block-uniform (0..3)
        float nc = c * c1 - s * s1;
        s = c * s1 + s * c1;
        c = nc;
    }
    peIJ[(m * NN + i) * NN + j] = make_float2(c, s);
}

// ---------------------------------------------------------------------------
// Kernel 1 (merged convA+convB): blocks 0..95 = convA (emb -> A' split-bf16),
// blocks 96..351 = convB (x -> Bre split-bf16; Bim derived in e_mfma).
// ---------------------------------------------------------------------------
__global__ void convAB_kernel(const float* __restrict__ er, const float* __restrict__ ei,
                              const float* __restrict__ xr, const float* __restrict__ xi,
                              unsigned int* __restrict__ AbfHi, unsigned int* __restrict__ AbfLo,
                              unsigned int* __restrict__ BreHi, unsigned int* __restrict__ BreLo) {
    if (blockIdx.x < 96) {
        int tmh = blockIdx.x;             // 0..95
        int base = tmh * QDD * DD;
#pragma unroll
        for (int it = 0; it < 8; ++it) {
            int idx = threadIdx.x + it * 256;  // q*128+D
            float ar = er[base + idx];
            float ai = ei[base + idx];
            unsigned short arh, arl, aih, ail;
            bfsplit(ar, arh, arl);
            bfsplit(ai, aih, ail);
            AbfHi[base + idx] = (unsigned int)arh | ((unsigned int)aih << 16);
            AbfLo[base + idx] = (unsigned int)arl | ((unsigned int)ail << 16);
        }
        return;
    }
    int bid = blockIdx.x - 96;            // 0..255 = 32 bm x 8 Dg
    int bm = bid >> 3;
    int Dg = bid & 7;
    int D0 = Dg * 16;
    int tid = threadIdx.x;

    __shared__ float sxr[16][257];
    __shared__ float sxi[16][257];

    const float* xrp = xr + (size_t)bm * DD * NN;
    const float* xip = xi + (size_t)bm * DD * NN;
#pragma unroll
    for (int it = 0; it < 16; ++it) {
        int i2 = tid + it * 256;
        int r = i2 >> 8, c = i2 & 255;
        sxr[r][c] = xrp[(size_t)(D0 + r) * NN + c];
        sxi[r][c] = xip[(size_t)(D0 + r) * NN + c];
    }
    __syncthreads();

    int n = tid;
    unsigned int reh[16], rel_[16];
#pragma unroll
    for (int d = 0; d < 16; ++d) {
        float br = sxr[d][n];
        float bi = sxi[d][n];
        unsigned short brh, brl, bih, bil;
        bfsplit(br, brh, brl);
        bfsplit(bi, bih, bil);
        reh[d]  = (unsigned int)brh | ((unsigned int)(bih ^ 0x8000) << 16);
        rel_[d] = (unsigned int)brl | ((unsigned int)(bil ^ 0x8000) << 16);
    }
    size_t ob = (size_t)bm * 32768 + (size_t)n * 128 + D0;
#pragma unroll
    for (int w = 0; w < 4; ++w) {
        ((uint4*)(BreHi + ob))[w] = make_uint4(reh[4*w], reh[4*w+1], reh[4*w+2], reh[4*w+3]);
        ((uint4*)(BreLo + ob))[w] = make_uint4(rel_[4*w], rel_[4*w+1], rel_[4*w+2], rel_[4*w+3]);
    }
}

// ---------------------------------------------------------------------------
// Kernel 2 (e_mfma v5 = v4 + FUSED qe): block = (pair, h, nhalf).
// ---------------------------------------------------------------------------
__global__ __launch_bounds__(256, 2)
void e_mfma_kernel(const unsigned short* __restrict__ AbfHi,
                   const unsigned short* __restrict__ AbfLo,
                   const unsigned short* __restrict__ BreHi,
                   const unsigned short* __restrict__ BreLo,
                   const float* __restrict__ encr, const float* __restrict__ enci,
                   float2* __restrict__ E,
                   float2* __restrict__ QE,
                   unsigned int* __restrict__ EaHi, unsigned int* __restrict__ EaLo,
                   unsigned int* __restrict__ KbHi, unsigned int* __restrict__ KbLo) {
    int bid = blockIdx.x;                 // 512 = 8 xcd x 64 idx
    int xcd = bid & 7;
    int idx = bid >> 3;                   // 0..63
    int pair = xcd * 4 + (idx & 3);       // b*MM+m (XCD-pinned B panels)
    int h = (idx >> 2) & 7;               // 0..7
    int nhalf = idx >> 5;                 // 0..1
    int b = pair >> 2, m = pair & 3;
    int tid = threadIdx.x;
    int wav = tid >> 6, lane = tid & 63;
    int lo = lane & 15, hi = lane >> 4;

    const unsigned short* AH[3];
    const unsigned short* AL[3];
#pragma unroll
    for (int t = 0; t < 3; ++t) {
        size_t aoff = ((size_t)((t * MM + m) * NHH + h)) * QDD * 256;
        AH[t] = AbfHi + aoff;
        AL[t] = AbfLo + aoff;
    }
    size_t boff = (size_t)pair * 256 * 256;
    const unsigned short* BrH = BreHi + boff;
    const unsigned short* BrL = BreLo + boff;

    f32x4 accRe[3][2], accIm[3][2];
#pragma unroll
    for (int t = 0; t < 3; ++t)
#pragma unroll
        for (int nt = 0; nt < 2; ++nt) {
            accRe[t][nt] = (f32x4)(0.f);
            accIm[t][nt] = (f32x4)(0.f);
        }

#pragma unroll
    for (int ks = 0; ks < 8; ++ks) {
        int k0 = ks * 32;
        int arow = lo * 256 + k0 + hi * 8;
        bf16x8 aH[3], aL[3];
#pragma unroll
        for (int t = 0; t < 3; ++t) {
            aH[t] = *(const bf16x8*)(AH[t] + arow);
            aL[t] = *(const bf16x8*)(AL[t] + arow);
        }
#pragma unroll
        for (int nt = 0; nt < 2; ++nt) {
            int n0 = nhalf * 128 + (wav * 2 + nt) * 16;
            size_t brow = (size_t)(n0 + lo) * 256 + k0 + hi * 8;
            bf16x8 brh = *(const bf16x8*)(BrH + brow);
            bf16x8 brl = *(const bf16x8*)(BrL + brow);
            bf16x8 bih = derive_im(brh);
            bf16x8 bil = derive_im(brl);
#pragma unroll
            for (int t = 0; t < 3; ++t) {
                accRe[t][nt] = __builtin_amdgcn_mfma_f32_16x16x32_bf16(aH[t], brh, accRe[t][nt], 0, 0, 0);
                accRe[t][nt] = __builtin_amdgcn_mfma_f32_16x16x32_bf16(aH[t], brl, accRe[t][nt], 0, 0, 0);
                accRe[t][nt] = __builtin_amdgcn_mfma_f32_16x16x32_bf16(aL[t], brh, accRe[t][nt], 0, 0, 0);
                accIm[t][nt] = __builtin_amdgcn_mfma_f32_16x16x32_bf16(aH[t], bih, accIm[t][nt], 0, 0, 0);
                accIm[t][nt] = __builtin_amdgcn_mfma_f32_16x16x32_bf16(aH[t], bil, accIm[t][nt], 0, 0, 0);
                accIm[t][nt] = __builtin_amdgcn_mfma_f32_16x16x32_bf16(aL[t], bih, accIm[t][nt], 0, 0, 0);
            }
        }
    }

    int bh = b * NHH + h;

    // --- fused qe: QE[b,m,h,i] = sum_q conj(E0[q,i])*enc0[m,h,q] ---
    {
        float cr[4], ci[4];
#pragma unroll
        for (int reg = 0; reg < 4; ++reg) {
            int q = hi * 4 + reg;
            int eb = (m * NHH + h) * QDD + q;
            cr[reg] = encr[eb];
            ci[reg] = enci[eb];
        }
#pragma unroll
        for (int nt = 0; nt < 2; ++nt) {
            int n0 = nhalf * 128 + (wav * 2 + nt) * 16;
            float sr = 0.f, si = 0.f;
#pragma unroll
            for (int reg = 0; reg < 4; ++reg) {
                float erv = accRe[0][nt][reg];
                float eiv = accIm[0][nt][reg];
                sr = fmaf(erv, cr[reg], fmaf( eiv, ci[reg], sr));
                si = fmaf(erv, ci[reg], fmaf(-eiv, cr[reg], si));
            }
            sr += __shfl_xor(sr, 16); si += __shfl_xor(si, 16);
            sr += __shfl_xor(sr, 32); si += __shfl_xor(si, 32);
            if (hi == 0)
                QE[(size_t)((b * MM + m) * NHH + h) * NN + n0 + lo] = make_float2(sr, si);
        }
    }

    // t=0: Ea fragments ; t=1: Kb fragments ; t=2: E float2 (V).
#pragma unroll
    for (int t = 0; t < 3; ++t) {
        size_t ebase = (size_t)((((t * BB + b) * MM + m) * NHH + h) * QDD) * NN;
#pragma unroll
        for (int nt = 0; nt < 2; ++nt) {
            int n0 = nhalf * 128 + (wav * 2 + nt) * 16;
            if (t == 2) {
#pragma unroll
                for (int reg = 0; reg < 4; ++reg) {
                    int q = hi * 4 + reg;
                    E[ebase + (size_t)q * NN + n0 + lo] =
                        make_float2(accRe[t][nt][reg], accIm[t][nt][reg]);
                }
            }
            if (t < 2) {
                unsigned int hiU[4], loU[4];
#pragma unroll
                for (int reg = 0; reg < 4; ++reg) {
                    unsigned short rh, rl, ih, il;
                    bfsplit(accRe[t][nt][reg], rh, rl);
                    bfsplit(accIm[t][nt][reg], ih, il);
                    hiU[reg] = (unsigned int)rh | ((unsigned int)ih << 16);
                    loU[reg] = (unsigned int)rl | ((unsigned int)il << 16);
                }
                int r = n0 >> 4;
                size_t fo = (size_t)bh * 16384 + (size_t)((r * 4 + m) * 64 + lane) * 4;
                unsigned int* tH = (t == 0) ? EaHi : KbHi;
                unsigned int* tL = (t == 0) ? EaLo : KbLo;
                *(uint4*)(tH + fo) = make_uint4(hiU[0], hiU[1], hiU[2], hiU[3]);
                *(uint4*)(tL + fo) = make_uint4(loU[0], loU[1], loU[2], loU[3]);
            }
        }
    }
}

// ---------------------------------------------------------------------------
// Kernel 3 (a_mfma v4, coalesced + j-split): 512 blocks.
// ---------------------------------------------------------------------------
__global__ __launch_bounds__(256, 2)
void a_mfma_kernel(const unsigned short* __restrict__ EaHi,
                   const unsigned short* __restrict__ EaLo,
                   const unsigned short* __restrict__ KbHi,
                   const unsigned short* __restrict__ KbLo,
                   const float2* __restrict__ QE,
                   const float2* __restrict__ peIJ,
                   float2* __restrict__ Scores) {
    int bid = blockIdx.x;                 // 512 = 8 xcd x 64 idx
    int xcd = bid & 7;
    int idx = bid >> 3;                   // 0..63
    int bh = xcd * 8 + (idx & 7);         // K-panel XCD-pinned
    int iquad = (idx >> 3) & 3;           // 0..3
    int jhalf = idx >> 5;                 // 0..1
    int b = bh >> 3, h = bh & 7;
    int tid = threadIdx.x;
    int wav = tid >> 6, lane = tid & 63;
    int lo = lane & 15, hi = lane >> 4;
    int it = iquad * 4 + wav;             // this wave's i-tile (0..15)

    const unsigned short* EaH = EaHi + (size_t)bh * 32768;
    const unsigned short* EaL = EaLo + (size_t)bh * 32768;
    const unsigned short* KbH = KbHi + (size_t)bh * 32768;
    const unsigned short* KbL = KbLo + (size_t)bh * 32768;

    f32x4 accRe[8], accIm[8];
#pragma unroll
    for (int nt = 0; nt < 8; ++nt) { accRe[nt] = (f32x4)(0.f); accIm[nt] = (f32x4)(0.f); }

#pragma unroll
    for (int ks = 0; ks < 4; ++ks) {
        size_t arow = (size_t)((it * 4 + ks) * 64 + lane) * 8;   // coalesced
        bf16x8 aH = *(const bf16x8*)(EaH + arow);
        bf16x8 aL = *(const bf16x8*)(EaL + arow);
#pragma unroll
        for (int nt = 0; nt < 8; ++nt) {
            int jt = jhalf * 8 + nt;
            size_t brow = (size_t)((jt * 4 + ks) * 64 + lane) * 8;  // coalesced
            bf16x8 brh = *(const bf16x8*)(KbH + brow);
            bf16x8 brl = *(const bf16x8*)(KbL + brow);
            bf16x8 bih = derive_im2(brh);
            bf16x8 bil = derive_im2(brl);
            accRe[nt] = __builtin_amdgcn_mfma_f32_16x16x32_bf16(aH, brh, accRe[nt], 0, 0, 0);
            accRe[nt] = __builtin_amdgcn_mfma_f32_16x16x32_bf16(aH, brl, accRe[nt], 0, 0, 0);
            accRe[nt] = __builtin_amdgcn_mfma_f32_16x16x32_bf16(aL, brh, accRe[nt], 0, 0, 0);
            accIm[nt] = __builtin_amdgcn_mfma_f32_16x16x32_bf16(aH, bih, accIm[nt], 0, 0, 0);
            accIm[nt] = __builtin_amdgcn_mfma_f32_16x16x32_bf16(aH, bil, accIm[nt], 0, 0, 0);
            accIm[nt] = __builtin_amdgcn_mfma_f32_16x16x32_bf16(aL, bih, accIm[nt], 0, 0, 0);
        }
    }

    // epilogue: + sum_m QE[b,m,h,i]*pe[m,i,j]; write Scores.
    float2 qe[MM][4];
#pragma unroll
    for (int m = 0; m < MM; ++m)
#pragma unroll
        for (int reg = 0; reg < 4; ++reg) {
            int i = it * 16 + hi * 4 + reg;
            qe[m][reg] = QE[(size_t)((b * MM + m) * NHH + h) * NN + i];
        }

#pragma unroll
    for (int nt = 0; nt < 8; ++nt) {
#pragma unroll
        for (int reg = 0; reg < 4; ++reg) {
            int i = it * 16 + hi * 4 + reg;
            int j = (jhalf * 8 + nt) * 16 + lo;
            float ar = accRe[nt][reg];
            float ai = accIm[nt][reg];
#pragma unroll
            for (int m = 0; m < MM; ++m) {
                float2 p = peIJ[(size_t)(m * NN + i) * NN + j];
                float2 e1 = qe[m][reg];
                ar = fmaf(e1.x, p.x, fmaf(-e1.y, p.y, ar));
                ai = fmaf(e1.x, p.y, fmaf( e1.y, p.x, ai));
            }
            Scores[(size_t)(bh * NN + i) * NN + j] = make_float2(ar, ai);
        }
    }
}

// ---------------------------------------------------------------------------
// Kernel 4 (v3: LDS-tiled transpose, coalesced AwT writes + fused PA):
// Block = (bh, itile of 16 i). Thread (ri,ci) = (tid>>4, tid&15) owns row
// i0+ri, cols j = ci*16..ci*16+15. Row reductions via 16-lane shfl.
// aw staged in LDS st[16][257]; 16 coalesced write passes (64B lines full).
// ---------------------------------------------------------------------------
__global__ void softmax_kernel(const float2* __restrict__ A,
                               const float2* __restrict__ peIJ,
                               float* __restrict__ AwT,
                               float2* __restrict__ PA) {
    int bid = blockIdx.x;                 // bh*16 + itile
    int bh = bid >> 4;
    int itile = bid & 15;
    int i0 = itile * 16;
    int tid = threadIdx.x;
    int ri = tid >> 4;                    // 0..15 row in tile
    int ci = tid & 15;                    // col group
    int i = i0 + ri;

    __shared__ float st[16][257];

    // load 16 cols of row i, compute v = |A|/4
    const float2* ap = A + (size_t)(bh * NN + i) * NN + ci * 16;
    float vv[16];
    float mx = -3.4e38f;
#pragma unroll
    for (int k = 0; k < 16; ++k) {
        float2 a = ap[k];
        vv[k] = sqrtf(fmaf(a.x, a.x, a.y * a.y)) * 0.25f;
        mx = fmaxf(mx, vv[k]);
    }
    // row max across 16 lanes
#pragma unroll
    for (int off = 1; off < 16; off <<= 1) mx = fmaxf(mx, __shfl_xor(mx, off));
    // exp + sum
    float sm = 0.f;
#pragma unroll
    for (int k = 0; k < 16; ++k) { vv[k] = __expf(vv[k] - mx); sm += vv[k]; }
#pragma unroll
    for (int off = 1; off < 16; off <<= 1) sm += __shfl_xor(sm, off);
    float inv = 1.f / sm;

    // aw -> LDS; fused PA partials
    float par[MM], pai[MM];
#pragma unroll
    for (int m = 0; m < MM; ++m) { par[m] = 0.f; pai[m] = 0.f; }
#pragma unroll
    for (int k = 0; k < 16; ++k) {
        float aw = vv[k] * inv;
        st[ri][ci * 16 + k] = aw;
#pragma unroll
        for (int m = 0; m < MM; ++m) {
            float2 p = peIJ[(size_t)(m * NN + i) * NN + ci * 16 + k];
            par[m] = fmaf(p.x, aw, par[m]);
            pai[m] = fmaf(p.y, aw, pai[m]);
        }
    }
#pragma unroll
    for (int m = 0; m < MM; ++m) {
#pragma unroll
        for (int off = 1; off < 16; off <<= 1) {
            par[m] += __shfl_xor(par[m], off);
            pai[m] += __shfl_xor(pai[m], off);
        }
    }
    if (ci == 0) {
        int b = bh >> 3, h = bh & 7;
#pragma unroll
        for (int m = 0; m < MM; ++m)
            PA[(size_t)((b * MM + m) * NHH + h) * NN + i] = make_float2(par[m], pai[m]);
    }
    __syncthreads();

    // coalesced transposed write: pass p writes j = p*16 + jg for all 16 i
    int jg = tid >> 4;                    // 0..15
    int il = tid & 15;                    // 0..15
#pragma unroll
    for (int p = 0; p < 16; ++p) {
        int j = p * 16 + jg;
        AwT[(size_t)(bh * NN + j) * NN + i0 + il] = st[il][j];
    }
}

// ---------------------------------------------------------------------------
// Kernel 5 (qh-split + XCD swizzle, PA precomputed): 512 blocks.
// ---------------------------------------------------------------------------
__global__ __launch_bounds__(512)
void res_kernel(const float2* __restrict__ E, const float* __restrict__ AwT,
                const float2* __restrict__ PA,
                const float* __restrict__ encr, const float* __restrict__ enci,
                float2* __restrict__ Res) {
    int bid = blockIdx.x;
    int xcd = bid & 7;
    int idx = bid >> 3;                   // 0..63
    int bh = xcd * 8 + (idx & 7);         // b*NHH+h
    int mqh = idx >> 3;                   // 0..7
    int m  = mqh >> 1;
    int qh = mqh & 1;
    int h = bh & 7;
    int b = bh >> 3;
    int i = threadIdx.x & 255;
    int g = threadIdx.x >> 8;             // j-half 0/1

    __shared__ float2 sv[8][NN];          // 16 KB: this qh's 8 V rows
    __shared__ float2 spA[NN][8];         // 16 KB: g=1 partials (8 acc)
    __shared__ float2 senc[8];

    const float2* V = E + ((size_t)(((2 * BB + b) * MM + m) * NHH + h) * QDD + qh * 8) * NN;
    for (int i2 = threadIdx.x; i2 < 8 * NN; i2 += 512) sv[i2 >> 8][i2 & 255] = V[i2];
    if (threadIdx.x < 8) {
        int eb = ((MM + m) * NHH + h) * QDD + qh * 8 + threadIdx.x;   // enc[1,...]
        senc[threadIdx.x] = make_float2(encr[eb], enci[eb]);
    }
    __syncthreads();

    float accr[8], acci[8];
#pragma unroll
    for (int q = 0; q < 8; ++q) { accr[q] = 0.f; acci[q] = 0.f; }

    const float* awp = AwT + (size_t)((b * NHH + h) * NN) * NN + i;
    int j0 = g * (NN / 2);
    for (int j = j0; j < j0 + NN / 2; ++j) {
        float aw = awp[(size_t)j * NN];       // coalesced over i
#pragma unroll
        for (int q = 0; q < 8; ++q) {
            float2 vv = sv[q][j];             // wave-uniform -> broadcast
            accr[q] = fmaf(vv.x, aw, accr[q]);
            acci[q] = fmaf(vv.y, aw, acci[q]);
        }
    }

    if (g == 1) {
#pragma unroll
        for (int q = 0; q < 8; ++q) spA[i][q] = make_float2(accr[q], acci[q]);
    }
    __syncthreads();
    if (g == 0) {
#pragma unroll
        for (int q = 0; q < 8; ++q) {
            float2 o = spA[i][q];
            accr[q] += o.x; acci[q] += o.y;
        }
        float2 pa = PA[(size_t)((b * MM + m) * NHH + h) * NN + i];
        float par = pa.x, pai = pa.y;

        float2* rp = Res + ((size_t)((b * MM + m) * KO + h * QDD + qh * 8)) * NN + i;
#pragma unroll
        for (int q = 0; q < 8; ++q) {
            float2 e1 = senc[q];
            float rr = accr[q] + e1.x * par - e1.y * pai;
            float ri = acci[q] + e1.x * pai + e1.y * par;
            rp[(size_t)q * NN] = make_float2(rr, ri);
        }
    }
}

// ---------------------------------------------------------------------------
// Kernel 6 (DTILE=8 + XCD swizzle): out[b,m,D,n] = sum_k w_out*res.
// ---------------------------------------------------------------------------
__global__ void out_kernel(const float2* __restrict__ Res,
                           const float* __restrict__ wor, const float* __restrict__ woi,
                           float* __restrict__ out) {
    int bid = blockIdx.x;
    int xcd = bid & 7;
    int idx = bid >> 3;                   // 0..63
    int bm = xcd * 4 + (idx & 3);         // b*MM+m, 0..31
    int dt = idx >> 2;                    // 0..15
    int n = threadIdx.x;
    int D0 = dt * DTILE;
    int m = bm & 3;

    __shared__ float2 sw[DTILE][KO];      // 8 KB
    for (int i2 = threadIdx.x; i2 < DTILE * KO; i2 += 256) {
        int d = i2 >> 7, k = i2 & 127;
        int wb = (m * DD + D0 + d) * KO + k;
        sw[d][k] = make_float2(wor[wb], woi[wb]);
    }
    __syncthreads();

    const float2* rp = Res + (size_t)(bm * KO) * NN + n;
    float ar[DTILE], ai[DTILE];
#pragma unroll
    for (int d = 0; d < DTILE; ++d) { ar[d] = 0.f; ai[d] = 0.f; }

    for (int k = 0; k < KO; ++k) {
        float2 r = rp[(size_t)k * NN];    // coalesced
#pragma unroll
        for (int d = 0; d < DTILE; ++d) {
            float2 w = sw[d][k];          // broadcast
            ar[d] = fmaf(w.x, r.x, fmaf(-w.y, r.y, ar[d]));
            ai[d] = fmaf(w.x, r.y, fmaf( w.y, r.x, ai[d]));
        }
    }
#pragma unroll
    for (int d = 0; d < DTILE; ++d) {
        size_t ob = (size_t)(bm * DD + D0 + d) * NN + n;
        out[ob] = ar[d];
        out[(size_t)BB * MM * DD * NN + ob] = ai[d];
    }
}

// ---------------------------------------------------------------------------
extern "C" void kernel_launch(void* const* d_in, const int* in_sizes, int n_in,
                              void* d_out, int out_size, void* d_ws, size_t ws_size,
                              hipStream_t stream) {
    (void)in_sizes; (void)n_in; (void)out_size; (void)ws_size;

    const float* x_re   = (const float*)d_in[0];
    const float* x_im   = (const float*)d_in[1];
    const float* emb_re = (const float*)d_in[2];
    const float* emb_im = (const float*)d_in[3];
    const float* enc_re = (const float*)d_in[4];
    const float* enc_im = (const float*)d_in[5];
    const float* out_re = (const float*)d_in[6];
    const float* out_im = (const float*)d_in[7];
    float* out = (float*)d_out;

    // Workspace layout (floats). Total ~155.7 MB.
    float* ws = (float*)d_ws;
    size_t off = 0;
    float2* peIJ = (float2*)(ws + off); off += (size_t)MM * NN * NN * 2;          // 524288
    float2* peT  = (float2*)(ws + off); off += (size_t)MM * NN * NN * 2;          // 524288 (dead; hosts PA)
    float2* E    = (float2*)(ws + off); off += (size_t)3 * BB * MM * NHH * QDD * NN * 2; // 25165824
    float2* QE   = (float2*)(ws + off); off += (size_t)BB * MM * NHH * NN * 2;    // 131072
    float2* A    = (float2*)(ws + off); off += (size_t)BB * NHH * NN * NN * 2;    // 8388608 fl
    float*  AwT  = (float*)(ws + off);  off += (size_t)BB * NHH * NN * NN;        // 4194304 fl

    unsigned int* AbfHi = (unsigned int*)A;
    unsigned int* AbfLo = AbfHi + (size_t)96 * QDD * DD;
    unsigned int* BreHi = AbfLo + (size_t)96 * QDD * DD;
    unsigned int* BreLo = BreHi + (size_t)32 * 256 * 128;

    unsigned int* EaHi = (unsigned int*)AwT;                      // 4 x 1048576 uints
    unsigned int* EaLo = EaHi + (size_t)64 * 16384;               //  = 16.78MB exact
    unsigned int* KbHi = EaLo + (size_t)64 * 16384;
    unsigned int* KbLo = KbHi + (size_t)64 * 16384;

    float2* Scores = A;   // full 33.5MB A region
    float2* Res    = A;   // first 8.4MB of A region, after Scores is dead
    float2* PA     = peT; // 1MB needed; peT region (2MB) is dead

    pe_kernel<<<MM * NN, 256, 0, stream>>>(peIJ);
    convAB_kernel<<<96 + 256, 256, 0, stream>>>(emb_re, emb_im, x_re, x_im,
                                                AbfHi, AbfLo, BreHi, BreLo);
    e_mfma_kernel<<<512, 256, 0, stream>>>(
        (const unsigned short*)AbfHi, (const unsigned short*)AbfLo,
        (const unsigned short*)BreHi, (const unsigned short*)BreLo,
        enc_re, enc_im, E, QE,
        EaHi, EaLo, KbHi, KbLo);
    a_mfma_kernel<<<512, 256, 0, stream>>>(
        (const unsigned short*)EaHi, (const unsigned short*)EaLo,
        (const unsigned short*)KbHi, (const unsigned short*)KbLo,
        QE, peIJ, Scores);
    softmax_kernel<<<BB * NHH * 16, 256, 0, stream>>>(Scores, peIJ, AwT, PA);
    res_kernel<<<BB * MM * NHH * 2, 512, 0, stream>>>(E, AwT, PA, enc_re, enc_im, Res);
    out_kernel<<<BB * MM * (DD / DTILE), 256, 0, stream>>>(Res, out_re, out_im, out);
}